// Round 1
// baseline (2508.441 us; speedup 1.0000x reference)
//
#include <hip/hip_runtime.h>

// SheafGluingPoly: out = sum_k poly[k] * (L^k c0), L = sheaf Laplacian over E edges.
// B=4, M=50000, D=8, E=1.6e6, LAM=1.0, POLY_K=3.

#define BLOCK 256

// 32 threads per edge: lane = b*8 + t  (b in [0,4), t in [0,8))
__global__ __launch_bounds__(BLOCK) void edge_kernel(
    const float* __restrict__ p,      // (B, M, D)
    const int*   __restrict__ src,
    const int*   __restrict__ dst,
    const float* __restrict__ Rs,     // (E, D, D)
    const float* __restrict__ Rd,     // (E, D, D)
    float*       __restrict__ acc,    // (B, M, D), pre-zeroed
    int E, int M)
{
    long tid = (long)blockIdx.x * BLOCK + threadIdx.x;
    int e = (int)(tid >> 5);
    if (e >= E) return;
    int lane = (int)tid & 31;
    int t = lane & 7;   // row / output-component index
    int b = lane >> 3;  // batch index

    int s = src[e];
    int d = dst[e];

    // row t of R_src[e], R_dst[e]  (coalesced float4 loads; wave covers 2 edges = 2KB)
    const float* rs = Rs + (size_t)e * 64 + t * 8;
    const float* rd = Rd + (size_t)e * 64 + t * 8;
    float4 rs0 = *(const float4*)(rs);
    float4 rs1 = *(const float4*)(rs + 4);
    float4 rd0 = *(const float4*)(rd);
    float4 rd1 = *(const float4*)(rd + 4);

    // gathered p vectors (same address across the 8-lane group -> broadcast)
    const float* ps = p + ((size_t)b * M + s) * 8;
    const float* pd = p + ((size_t)b * M + d) * 8;
    float4 ps0 = *(const float4*)(ps);
    float4 ps1 = *(const float4*)(ps + 4);
    float4 pd0 = *(const float4*)(pd);
    float4 pd1 = *(const float4*)(pd + 4);

    // r[b][t] = (R_src[e] @ p_src)[t] - (R_dst[e] @ p_dst)[t]
    float r = rs0.x * ps0.x + rs0.y * ps0.y + rs0.z * ps0.z + rs0.w * ps0.w
            + rs1.x * ps1.x + rs1.y * ps1.y + rs1.z * ps1.z + rs1.w * ps1.w
            - rd0.x * pd0.x - rd0.y * pd0.y - rd0.z * pd0.z - rd0.w * pd0.w
            - rd1.x * pd1.x - rd1.y * pd1.y - rd1.z * pd1.z - rd1.w * pd1.w;

    // c_src[t] = (R_src^T r)[t],  c_dst[t] = -(R_dst^T r)[t]
    // column t loads hit L1 (lines already fetched by the row loads above).
    const float* colS = Rs + (size_t)e * 64 + t;
    const float* colD = Rd + (size_t)e * 64 + t;
    float cs = 0.f, cd = 0.f;
#pragma unroll
    for (int a = 0; a < 8; a++) {
        float ra = __shfl(r, a, 8);   // all-gather r over the 8-lane group
        cs += colS[a * 8] * ra;
        cd += colD[a * 8] * ra;
    }

    atomicAdd(acc + ((size_t)b * M + s) * 8 + t, cs);
    atomicAdd(acc + ((size_t)b * M + d) * 8 + t, -cd);
}

__global__ __launch_bounds__(BLOCK) void init_out_kernel(
    const float4* __restrict__ c0, const float* __restrict__ poly,
    float4* __restrict__ out, int n4)
{
    int i = blockIdx.x * BLOCK + threadIdx.x;
    if (i >= n4) return;
    float a = poly[0];
    float4 c = c0[i];
    out[i] = make_float4(a * c.x, a * c.y, a * c.z, a * c.w);
}

__global__ __launch_bounds__(BLOCK) void axpy_kernel(
    const float4* __restrict__ v, const float* __restrict__ poly, int k,
    float4* __restrict__ out, int n4)
{
    int i = blockIdx.x * BLOCK + threadIdx.x;
    if (i >= n4) return;
    float a = poly[k];
    float4 vv = v[i];
    float4 o = out[i];
    out[i] = make_float4(o.x + a * vv.x, o.y + a * vv.y,
                         o.z + a * vv.z, o.w + a * vv.w);
}

extern "C" void kernel_launch(void* const* d_in, const int* in_sizes, int n_in,
                              void* d_out, int out_size, void* d_ws, size_t ws_size,
                              hipStream_t stream) {
    const float* c0   = (const float*)d_in[0];
    const int*   src  = (const int*)d_in[1];
    const int*   dst  = (const int*)d_in[2];
    const float* Rs   = (const float*)d_in[3];
    const float* Rd   = (const float*)d_in[4];
    const float* poly = (const float*)d_in[5];
    float* out = (float*)d_out;

    const int B = 4, D = 8;
    const int E = in_sizes[1];
    const int M = in_sizes[0] / (B * D);
    const size_t nElem = (size_t)B * M * D;   // 1.6M floats = 6.4 MB
    const int n4 = (int)(nElem / 4);

    float* bufA = (float*)d_ws;
    float* bufB = bufA + nElem;

    init_out_kernel<<<(n4 + BLOCK - 1) / BLOCK, BLOCK, 0, stream>>>(
        (const float4*)c0, poly, (float4*)out, n4);

    const float* p = c0;
    float* accs[3] = { bufA, bufB, bufA };
    long nEdgeThreads = (long)E * 32;
    int edgeBlocks = (int)((nEdgeThreads + BLOCK - 1) / BLOCK);

    for (int k = 1; k <= 3; k++) {
        float* acc = accs[k - 1];
        hipMemsetAsync(acc, 0, nElem * sizeof(float), stream);
        edge_kernel<<<edgeBlocks, BLOCK, 0, stream>>>(p, src, dst, Rs, Rd, acc, E, M);
        axpy_kernel<<<(n4 + BLOCK - 1) / BLOCK, BLOCK, 0, stream>>>(
            (const float4*)acc, poly, k, (float4*)out, n4);
        p = acc;
    }
}